// Round 10
// baseline (560.026 us; speedup 1.0000x reference)
//
#include <hip/hip_runtime.h>
#include <cstddef>
#include <cstdint>

typedef _Float16 f16;
typedef _Float16 f16x8 __attribute__((ext_vector_type(8)));
typedef float f32x4 __attribute__((ext_vector_type(4)));

constexpr int ND = 30000, NG = 60000, NS = 15000;
constexpr float BN_EPS = 1e-5f;
constexpr int NBUCK = 64;      // buckets per edge type
constexpr int TBUCK = 6 * NBUCK;
constexpr int PCHUNK = 4096;   // edges per partition block

static inline int cdiv(int a, int b){ return (a + b - 1) / b; }

// ================= bucketed CSR construction =================

struct BDesc {
    const int* src[6]; const int* dst[6];
    int Ebase[7]; int shift[6]; int N[6];
    int* bCnt; int* bBase; int* bCursor;
    uint2* packed;
    int* offs[6]; int* csr[6];
};

__global__ __launch_bounds__(256) void bhist_k(BDesc bd){
    __shared__ int hist[TBUCK];
    int tid = threadIdx.x;
    for (int i = tid; i < TBUCK; i += 256) hist[i] = 0;
    __syncthreads();
    int Etot = bd.Ebase[6];
    #pragma unroll
    for (int u = 0; u < 16; u++){
        int e = blockIdx.x * PCHUNK + u * 256 + tid;
        if (e < Etot){
            int t = 0;
            #pragma unroll
            for (int i = 1; i < 6; i++) if (e >= bd.Ebase[i]) t = i;
            int d = bd.dst[t][e - bd.Ebase[t]];
            atomicAdd(&hist[t * NBUCK + (d >> bd.shift[t])], 1);
        }
    }
    __syncthreads();
    for (int i = tid; i < TBUCK; i += 256)
        if (hist[i]) atomicAdd(&bd.bCnt[i], hist[i]);
}

__global__ __launch_bounds__(512) void bscan_k(BDesc bd){
    __shared__ int sh[TBUCK];
    int tid = threadIdx.x;
    int my = (tid < TBUCK) ? bd.bCnt[tid] : 0;
    if (tid < TBUCK) sh[tid] = my;
    __syncthreads();
    for (int d = 1; d < TBUCK; d <<= 1){
        int v = (tid < TBUCK) ? sh[tid] : 0;
        int add = (tid >= d && tid < TBUCK) ? sh[tid - d] : 0;
        __syncthreads();
        if (tid < TBUCK) sh[tid] = v + add;
        __syncthreads();
    }
    if (tid < TBUCK){
        int excl = sh[tid] - my;
        bd.bBase[tid] = excl;
        bd.bCursor[tid] = excl;
    }
    if (tid == 0) bd.bBase[TBUCK] = sh[TBUCK - 1];
}

__global__ __launch_bounds__(256) void bpart_k(BDesc bd){
    __shared__ int hist[TBUCK];
    __shared__ int basesh[TBUCK];
    int tid = threadIdx.x;
    for (int i = tid; i < TBUCK; i += 256) hist[i] = 0;
    __syncthreads();
    int Etot = bd.Ebase[6];
    int mb[16], mr[16], ms[16], md[16];
    #pragma unroll
    for (int u = 0; u < 16; u++){
        int e = blockIdx.x * PCHUNK + u * 256 + tid;
        mb[u] = -1;
        if (e < Etot){
            int t = 0;
            #pragma unroll
            for (int i = 1; i < 6; i++) if (e >= bd.Ebase[i]) t = i;
            int le = e - bd.Ebase[t];
            int s = bd.src[t][le], d = bd.dst[t][le];
            int b = t * NBUCK + (d >> bd.shift[t]);
            mr[u] = atomicAdd(&hist[b], 1);
            mb[u] = b; ms[u] = s; md[u] = d;
        }
    }
    __syncthreads();
    for (int i = tid; i < TBUCK; i += 256)
        basesh[i] = hist[i] ? atomicAdd(&bd.bCursor[i], hist[i]) : 0;
    __syncthreads();
    #pragma unroll
    for (int u = 0; u < 16; u++){
        if (mb[u] >= 0){
            int pos = basesh[mb[u]] + mr[u];
            bd.packed[pos] = make_uint2((unsigned)ms[u], (unsigned)md[u]);
        }
    }
}

// one block per bucket: count -> scan -> offs -> fill (all LDS-local)
__global__ __launch_bounds__(256) void bucketCsr_k(BDesc bd){
    __shared__ int cnt[1024];
    __shared__ int sh[256];
    int b = blockIdx.x;
    int t = b >> 6;          // /NBUCK
    int bb = b & 63;
    int tid = threadIdx.x;
    int shift = bd.shift[t];
    int nodeBase = bb << shift;
    int Nt = bd.N[t];
    int span = 1 << shift;   // <= 1024
    int tbase = bd.bBase[t * NBUCK];
    int eBeg = bd.bBase[b], eEnd = bd.bBase[b + 1];
    int bLocal = eBeg - tbase;
    #pragma unroll
    for (int i = 0; i < 4; i++) cnt[tid + i * 256] = 0;
    __syncthreads();
    for (int e = eBeg + tid; e < eEnd; e += 256)
        atomicAdd(&cnt[(int)bd.packed[e].y - nodeBase], 1);
    __syncthreads();
    int c0 = cnt[tid * 4], c1 = cnt[tid * 4 + 1], c2 = cnt[tid * 4 + 2], c3 = cnt[tid * 4 + 3];
    int s = c0 + c1 + c2 + c3;
    sh[tid] = s;
    __syncthreads();
    for (int d = 1; d < 256; d <<= 1){
        int v = sh[tid];
        int add = (tid >= d) ? sh[tid - d] : 0;
        __syncthreads();
        sh[tid] = v + add;
        __syncthreads();
    }
    int run = sh[tid] - s;
    int idx = tid * 4;
    int ex0 = run, ex1 = run + c0, ex2 = ex1 + c1, ex3 = ex2 + c2;
    if (idx     < span && nodeBase + idx     < Nt) bd.offs[t][nodeBase + idx]     = bLocal + ex0;
    if (idx + 1 < span && nodeBase + idx + 1 < Nt) bd.offs[t][nodeBase + idx + 1] = bLocal + ex1;
    if (idx + 2 < span && nodeBase + idx + 2 < Nt) bd.offs[t][nodeBase + idx + 2] = bLocal + ex2;
    if (idx + 3 < span && nodeBase + idx + 3 < Nt) bd.offs[t][nodeBase + idx + 3] = bLocal + ex3;
    cnt[idx] = ex0; cnt[idx + 1] = ex1; cnt[idx + 2] = ex2; cnt[idx + 3] = ex3;
    __syncthreads();
    for (int e = eBeg + tid; e < eEnd; e += 256){
        uint2 p = bd.packed[e];
        int lpos = atomicAdd(&cnt[(int)p.y - nodeBase], 1);
        bd.csr[t][bLocal + lpos] = (int)p.x;
    }
    if (bb == NBUCK - 1 && tid == 0)
        bd.offs[t][Nt] = bd.bBase[(t + 1) * NBUCK] - tbase;
}

// ================= prep: casts + weight transposes =================

struct CastDesc { const float* src[3]; f16* dst[3]; int base[4]; };

__global__ __launch_bounds__(256) void castAll_k(CastDesc cdsc){
    int idx = blockIdx.x * 256 + threadIdx.x;
    if (idx >= cdsc.base[3]) return;
    int t = 0;
    #pragma unroll
    for (int i = 1; i < 3; i++) if (idx >= cdsc.base[i]) t = i;
    int i4 = (idx - cdsc.base[t]) * 4;
    float4 v = *reinterpret_cast<const float4*>(cdsc.src[t] + i4);
    union { uint2 u; f16 h[4]; } o;
    o.h[0] = (f16)v.x; o.h[1] = (f16)v.y; o.h[2] = (f16)v.z; o.h[3] = (f16)v.w;
    *reinterpret_cast<uint2*>(cdsc.dst[t] + i4) = o.u;
}

struct WDesc {
    const float* W_in0; const float* W_in1; const float* W_in2;
    const float* W_fin; const float* Wl; const float* Wr;
    f16* Wint0; f16* Wint1; f16* Wint2; f16* Wfin_t; f16* Wcat_t;
};

__global__ __launch_bounds__(256) void weightAll_k(WDesc wd){
    int idx = blockIdx.x * 256 + threadIdx.x;
    if (idx < 32768){
        int c = idx >> 8, k = idx & 255;
        wd.Wint0[idx] = (f16)wd.W_in0[k * 128 + c];
    } else if (idx < 49152){
        int l = idx - 32768; int c = l >> 7, k = l & 127;
        wd.Wint1[l] = (f16)wd.W_in1[k * 128 + c];
    } else if (idx < 57344){
        int l = idx - 49152; int c = l >> 6, k = l & 63;
        wd.Wint2[l] = (f16)wd.W_in2[k * 128 + c];
    } else if (idx < 65536){
        int l = idx - 57344; int c = l >> 7, k = l & 127;
        wd.Wfin_t[l] = (f16)wd.W_fin[k * 64 + c];
    } else if (idx < 507904){
        int l = idx - 65536;
        int g = l / (384 * 128);
        int rem = l - g * (384 * 128);
        int c = rem / 384;
        int k = rem - c * 384;
        int L = g / 3, t = g - L * 3;
        const int e1s[3] = {1, 0, 2}, e2s[3] = {5, 3, 4};
        int e1 = e1s[t], e2 = e2s[t];
        float v;
        if (k < 128)      v = wd.Wl[(((size_t)L * 6 + e1) * 128 + k) * 128 + c];
        else if (k < 256) v = wd.Wl[(((size_t)L * 6 + e2) * 128 + (k - 128)) * 128 + c];
        else {
            int kr = k - 256;
            v = wd.Wr[(((size_t)L * 6 + e1) * 128 + kr) * 128 + c]
              + wd.Wr[(((size_t)L * 6 + e2) * 128 + kr) * 128 + c];
        }
        wd.Wcat_t[l] = (f16)v;
    }
}

// ================= fused gather-mean: 16-lane group per node, 2-stage pipeline =================
// Group (16 lanes) owns one node; lane li reads 16B segment li of each neighbor row.
// Batch v[8] accumulates while batch w[8] loads are in flight (vmcnt overlap).

struct GSeg { const int* offs; const int* csr; const uint4* h; uint4* A; int colPair4; int N; int base; };
struct GDesc { GSeg s[6]; const uint4* zrow; };

__device__ __forceinline__ f16x8 as_h8(uint4 v){
    union { uint4 u; f16x8 h; } c; c.u = v; return c.h;
}

__global__ __launch_bounds__(256) void gatherall_k(GDesc gd){
    int bid = blockIdx.x;
    int si = 0;
    #pragma unroll
    for (int t = 1; t < 6; t++) if (bid >= gd.s[t].base) si = t;
    GSeg sg = gd.s[si];
    int node = (bid - sg.base) * 16 + (threadIdx.x >> 4);
    if (node >= sg.N) return;
    int li = threadIdx.x & 15;
    int s = sg.offs[node], e = sg.offs[node + 1];
    const int* cp = sg.csr;
    const uint4* hp = sg.h;
    const uint4* zr = gd.zrow;
    f16x8 a = {};
    if (s < e){
        uint4 v0, v1, v2, v3, v4, v5, v6, v7;
        {
            const uint4* p0 = (s + 0 < e) ? (hp + (size_t)cp[s + 0] * 16) : zr;
            const uint4* p1 = (s + 1 < e) ? (hp + (size_t)cp[s + 1] * 16) : zr;
            const uint4* p2 = (s + 2 < e) ? (hp + (size_t)cp[s + 2] * 16) : zr;
            const uint4* p3 = (s + 3 < e) ? (hp + (size_t)cp[s + 3] * 16) : zr;
            const uint4* p4 = (s + 4 < e) ? (hp + (size_t)cp[s + 4] * 16) : zr;
            const uint4* p5 = (s + 5 < e) ? (hp + (size_t)cp[s + 5] * 16) : zr;
            const uint4* p6 = (s + 6 < e) ? (hp + (size_t)cp[s + 6] * 16) : zr;
            const uint4* p7 = (s + 7 < e) ? (hp + (size_t)cp[s + 7] * 16) : zr;
            v0 = p0[li]; v1 = p1[li]; v2 = p2[li]; v3 = p3[li];
            v4 = p4[li]; v5 = p5[li]; v6 = p6[li]; v7 = p7[li];
        }
        for (int j = s + 8; j < e; j += 8){
            const uint4* p0 = (j + 0 < e) ? (hp + (size_t)cp[j + 0] * 16) : zr;
            const uint4* p1 = (j + 1 < e) ? (hp + (size_t)cp[j + 1] * 16) : zr;
            const uint4* p2 = (j + 2 < e) ? (hp + (size_t)cp[j + 2] * 16) : zr;
            const uint4* p3 = (j + 3 < e) ? (hp + (size_t)cp[j + 3] * 16) : zr;
            const uint4* p4 = (j + 4 < e) ? (hp + (size_t)cp[j + 4] * 16) : zr;
            const uint4* p5 = (j + 5 < e) ? (hp + (size_t)cp[j + 5] * 16) : zr;
            const uint4* p6 = (j + 6 < e) ? (hp + (size_t)cp[j + 6] * 16) : zr;
            const uint4* p7 = (j + 7 < e) ? (hp + (size_t)cp[j + 7] * 16) : zr;
            uint4 w0 = p0[li], w1 = p1[li], w2 = p2[li], w3 = p3[li];
            uint4 w4 = p4[li], w5 = p5[li], w6 = p6[li], w7 = p7[li];
            a = a + as_h8(v0); a = a + as_h8(v1); a = a + as_h8(v2); a = a + as_h8(v3);
            a = a + as_h8(v4); a = a + as_h8(v5); a = a + as_h8(v6); a = a + as_h8(v7);
            v0 = w0; v1 = w1; v2 = w2; v3 = w3;
            v4 = w4; v5 = w5; v6 = w6; v7 = w7;
        }
        a = a + as_h8(v0); a = a + as_h8(v1); a = a + as_h8(v2); a = a + as_h8(v3);
        a = a + as_h8(v4); a = a + as_h8(v5); a = a + as_h8(v6); a = a + as_h8(v7);
    }
    float inv = (e > s) ? 1.0f / (float)(e - s) : 0.f;
    union { uint4 u; f16 h[8]; } pk;
    #pragma unroll
    for (int i = 0; i < 8; i++) pk.h[i] = (f16)((float)a[i] * inv);
    sg.A[(size_t)node * 32 + sg.colPair4 + li] = pk.u;
}

// ================= merged MFMA fp16 GEMM: global_load_lds + XOR swizzle =================

struct GemmSeg {
    const f16* A1; const f16* A2; const f16* Wt;
    const float* b1; const float* b2; void* out; float* stats;
    int lda1, lda2, ksplit, N, K, tileBase; float scale;
};
struct GemmDesc { GemmSeg s[3]; };

template<int BN, bool STATS, bool OUT16>
__global__ __launch_bounds__(256) void gemmAll_k(GemmDesc gd){
    constexpr int CF = BN / 16;
    __shared__ f16 As[128 * 64];
    __shared__ f16 Bs[BN * 64];
    __shared__ float ssum[BN];
    __shared__ float ssq[BN];
    int bid = blockIdx.x;
    int si = 0;
    #pragma unroll
    for (int t = 1; t < 3; t++) if (bid >= gd.s[t].tileBase) si = t;
    GemmSeg sg = gd.s[si];
    int tid = threadIdx.x;
    int wv = tid >> 6, lane = tid & 63;
    int row0 = (bid - sg.tileBase) * 128;
    int N = sg.N, K = sg.K;
    if (STATS && tid < BN){ ssum[tid] = 0.f; ssq[tid] = 0.f; }

    int rsub = lane >> 3;          // 0..7
    int seg  = lane & 7;
    int sseg = seg ^ rsub;         // inverse-swizzled global segment

    f32x4 acc[2][CF];
    #pragma unroll
    for (int rf = 0; rf < 2; rf++)
        #pragma unroll
        for (int cf = 0; cf < CF; cf++)
            acc[rf][cf] = (f32x4){0.f, 0.f, 0.f, 0.f};

    for (int k0 = 0; k0 < K; k0 += 64){
        const f16* Ab; int lda, kloc;
        if (k0 < sg.ksplit){ Ab = sg.A1; lda = sg.lda1; kloc = k0; }
        else               { Ab = sg.A2; lda = sg.lda2; kloc = k0 - sg.ksplit; }
        #pragma unroll
        for (int p = 0; p < 4; p++){
            int r = wv * 32 + p * 8 + rsub;
            const f16* srca = Ab + (size_t)(row0 + r) * lda + kloc + sseg * 8;
            __builtin_amdgcn_global_load_lds(
                (const __attribute__((address_space(1))) void*)srca,
                (__attribute__((address_space(3))) void*)&As[(wv * 32 + p * 8) * 64],
                16, 0, 0);
        }
        #pragma unroll
        for (int p = 0; p < BN / 32; p++){
            int c0 = wv * (BN / 4) + p * 8;
            const f16* srcb = sg.Wt + (size_t)(c0 + rsub) * K + k0 + sseg * 8;
            __builtin_amdgcn_global_load_lds(
                (const __attribute__((address_space(1))) void*)srcb,
                (__attribute__((address_space(3))) void*)&Bs[c0 * 64],
                16, 0, 0);
        }
        __syncthreads();
        #pragma unroll
        for (int kf = 0; kf < 2; kf++){
            int kidx = kf * 4 + (lane >> 4);
            int ar0 = wv * 32 + (lane & 15);
            int ar1 = ar0 + 16;
            f16x8 a0 = *reinterpret_cast<const f16x8*>(&As[ar0 * 64 + ((kidx ^ (ar0 & 7)) * 8)]);
            f16x8 a1 = *reinterpret_cast<const f16x8*>(&As[ar1 * 64 + ((kidx ^ (ar1 & 7)) * 8)]);
            #pragma unroll
            for (int cf = 0; cf < CF; cf++){
                int bc = cf * 16 + (lane & 15);
                f16x8 b = *reinterpret_cast<const f16x8*>(&Bs[bc * 64 + ((kidx ^ (bc & 7)) * 8)]);
                acc[0][cf] = __builtin_amdgcn_mfma_f32_16x16x32_f16(a0, b, acc[0][cf], 0, 0, 0);
                acc[1][cf] = __builtin_amdgcn_mfma_f32_16x16x32_f16(a1, b, acc[1][cf], 0, 0, 0);
            }
        }
        __syncthreads();
    }
    int rbase = row0 + wv * 32 + ((lane >> 4) << 2);
    #pragma unroll
    for (int cf = 0; cf < CF; cf++){
        int col = cf * 16 + (lane & 15);
        float bias = 0.f;
        if (sg.b1) bias += sg.b1[col];
        if (sg.b2) bias += sg.b2[col];
        float ls = 0.f, lq = 0.f;
        #pragma unroll
        for (int rf = 0; rf < 2; rf++){
            #pragma unroll
            for (int q = 0; q < 4; q++){
                int gr = rbase + rf * 16 + q;
                if (gr < N){
                    float v = sg.scale * (acc[rf][cf][q] + bias);
                    if (OUT16) ((f16*)sg.out)[(size_t)gr * BN + col] = (f16)v;
                    else       ((float*)sg.out)[(size_t)gr * BN + col] = v;
                    ls += v; lq += v * v;
                }
            }
        }
        if (STATS){ atomicAdd(&ssum[col], ls); atomicAdd(&ssq[col], lq); }
    }
    if (STATS){
        __syncthreads();
        if (tid < BN){
            atomicAdd(&sg.stats[tid], ssum[tid]);
            atomicAdd(&sg.stats[128 + tid], ssq[tid]);
        }
    }
}

// ================= merged BN apply + ReLU (+ residual) =================

struct BnSeg { const f16* o; const float* stats; const float* g; const float* b; f16* h; int N; float invN; int residual; int idxBase; };
struct BnDesc { BnSeg s[3]; int total; };

__global__ __launch_bounds__(256) void bnAll_k(BnDesc bd){
    int idx = blockIdx.x * 256 + threadIdx.x;
    if (idx >= bd.total) return;
    int si = 0;
    #pragma unroll
    for (int t = 1; t < 3; t++) if (idx >= bd.s[t].idxBase) si = t;
    BnSeg sg = bd.s[si];
    int l = idx - sg.idxBase;
    int n = l >> 4, c8 = (l & 15) * 8;
    union { uint4 u; f16 h[8]; } ov;
    ov.u = *reinterpret_cast<const uint4*>(sg.o + (size_t)n * 128 + c8);
    float r[8];
    #pragma unroll
    for (int j = 0; j < 8; j++){
        int c = c8 + j;
        float mu  = sg.stats[c] * sg.invN;
        float var = sg.stats[128 + c] * sg.invN - mu * mu;
        float v = ((float)ov.h[j] - mu) * rsqrtf(var + BN_EPS) * sg.g[c] + sg.b[c];
        r[j] = v > 0.f ? v : 0.f;
    }
    f16* hp = sg.h + (size_t)n * 128 + c8;
    if (sg.residual){
        uint4 old = *reinterpret_cast<const uint4*>(hp);
        union { uint4 u; f16 h[8]; } ou; ou.u = old;
        #pragma unroll
        for (int j = 0; j < 8; j++) r[j] += (float)ou.h[j];
    }
    union { uint4 u; f16 h[8]; } pk;
    #pragma unroll
    for (int j = 0; j < 8; j++) pk.h[j] = (f16)r[j];
    *reinterpret_cast<uint4*>(hp) = pk.u;
}

// ================= host orchestration =================

extern "C" void kernel_launch(void* const* d_in, const int* in_sizes, int n_in,
                              void* d_out, int out_size, void* d_ws, size_t ws_size,
                              hipStream_t stream){
    const float* x_drug = (const float*)d_in[0];
    const float* x_gene = (const float*)d_in[1];
    const float* x_dis  = (const float*)d_in[2];
    const int* srcP[6] = {(const int*)d_in[3], (const int*)d_in[5], (const int*)d_in[7],
                          (const int*)d_in[9], (const int*)d_in[11], (const int*)d_in[13]};
    const int* dstP[6] = {(const int*)d_in[4], (const int*)d_in[6], (const int*)d_in[8],
                          (const int*)d_in[10], (const int*)d_in[12], (const int*)d_in[14]};
    const int  Et[6]   = {in_sizes[3], in_sizes[5], in_sizes[7], in_sizes[9], in_sizes[11], in_sizes[13]};
    const float* W_in[3] = {(const float*)d_in[15], (const float*)d_in[17], (const float*)d_in[19]};
    const float* b_in[3] = {(const float*)d_in[16], (const float*)d_in[18], (const float*)d_in[20]};
    const float* g_in  = (const float*)d_in[21];
    const float* bt_in = (const float*)d_in[22];
    const float* Wl    = (const float*)d_in[23];
    const float* Wr    = (const float*)d_in[24];
    const float* bl    = (const float*)d_in[25];
    const float* g_conv  = (const float*)d_in[26];
    const float* bt_conv = (const float*)d_in[27];
    const float* W_fin = (const float*)d_in[28];
    const float* b_fin = (const float*)d_in[29];
    float* out = (float*)d_out;

    // edge-type metadata (order: dg, gd, gs, sg, ds, sd)
    const int Ndst_t[6]     = {NG, ND, NS, NG, NS, ND};
    const int srcT[6]       = {0, 1, 1, 2, 0, 2};
    const int dstT[6]       = {1, 0, 2, 1, 2, 0};
    const int colPair4_t[6] = {0, 0, 0, 16, 16, 16};

    const int Nn[3]  = {ND, NG, NS};
    const int Kin[3] = {256, 128, 64};
    const float* xin[3] = {x_drug, x_gene, x_dis};

    // ---- workspace carve ----
    char* base = (char*)d_ws;
    size_t off = 0;
    auto alloc = [&](size_t bytes) -> char* {
        char* p = base + off; off += (bytes + 255) & ~(size_t)255; return p;
    };
    f16* h[3];  for (int t = 0; t < 3; t++) h[t]  = (f16*)alloc((size_t)Nn[t] * 128 * 2);
    f16* A[3];  for (int t = 0; t < 3; t++) A[t]  = (f16*)alloc((size_t)Nn[t] * 256 * 2);
    f16* xb[3]; for (int t = 0; t < 3; t++) xb[t] = (f16*)alloc((size_t)Nn[t] * Kin[t] * 2);
    f16* Wint[3]; for (int t = 0; t < 3; t++) Wint[t] = (f16*)alloc((size_t)128 * Kin[t] * 2);
    f16* Wfin_t = (f16*)alloc((size_t)64 * 128 * 2);
    f16* Wcat_t = (f16*)alloc((size_t)9 * 128 * 384 * 2);
    // o pool (aliased by packed edge buffer during CSR build, which finishes first)
    char* oPool = alloc((size_t)(ND + NG + NS) * 128 * 2);
    f16* o[3];
    o[0] = (f16*)oPool; o[1] = o[0] + (size_t)ND * 128; o[2] = o[1] + (size_t)NG * 128;
    uint2* packed = (uint2*)oPool;
    float* stats = (float*)alloc(12 * 256 * 4);
    // zero pool: bucket counters + 256B zero row
    int* zeroPool = (int*)alloc((size_t)(TBUCK + 64) * 4);
    int* bCnt = zeroPool;
    const uint4* zrow = (const uint4*)(zeroPool + TBUCK);
    int* bBase   = (int*)alloc((TBUCK + 1) * 4);
    int* bCursor = (int*)alloc(TBUCK * 4);
    int *offs[6], *csr[6];
    for (int t = 0; t < 6; t++) offs[t] = (int*)alloc((size_t)(Ndst_t[t] + 1) * 4);
    for (int t = 0; t < 6; t++) csr[t]  = (int*)alloc((size_t)Et[t] * 4);

    hipMemsetAsync(zeroPool, 0, (size_t)(TBUCK + 64) * 4, stream);
    hipMemsetAsync(stats, 0, 12 * 256 * 4, stream);

    // ---- bucketed CSR build ----
    BDesc bd;
    {
        int ecum = 0;
        for (int t = 0; t < 6; t++){
            bd.src[t] = srcP[t]; bd.dst[t] = dstP[t];
            bd.Ebase[t] = ecum; ecum += Et[t];
            int sft = 0; while (((Ndst_t[t] - 1) >> sft) >= NBUCK) sft++;
            bd.shift[t] = sft;
            bd.N[t] = Ndst_t[t];
            bd.offs[t] = offs[t]; bd.csr[t] = csr[t];
        }
        bd.Ebase[6] = ecum;
        bd.bCnt = bCnt; bd.bBase = bBase; bd.bCursor = bCursor;
        bd.packed = packed;
    }
    int Etot = bd.Ebase[6];
    bhist_k<<<cdiv(Etot, PCHUNK), 256, 0, stream>>>(bd);
    bscan_k<<<1, 512, 0, stream>>>(bd);
    bpart_k<<<cdiv(Etot, PCHUNK), 256, 0, stream>>>(bd);
    bucketCsr_k<<<TBUCK, 256, 0, stream>>>(bd);

    // ---- casts + weights ----
    CastDesc cds;
    {
        int b = 0;
        for (int t = 0; t < 3; t++){
            cds.src[t] = xin[t]; cds.dst[t] = xb[t];
            cds.base[t] = b; b += Nn[t] * Kin[t] / 4;
        }
        cds.base[3] = b;
    }
    castAll_k<<<cdiv(cds.base[3], 256), 256, 0, stream>>>(cds);
    WDesc wd = {W_in[0], W_in[1], W_in[2], W_fin, Wl, Wr,
                Wint[0], Wint[1], Wint[2], Wfin_t, Wcat_t};
    weightAll_k<<<cdiv(507904, 256), 256, 0, stream>>>(wd);

    int tiles[3]; for (int t = 0; t < 3; t++) tiles[t] = cdiv(Nn[t], 128);
    int tileBase[4] = {0, tiles[0], tiles[0] + tiles[1], tiles[0] + tiles[1] + tiles[2]};

    // ---- input stage ----
    {
        GemmDesc g{};
        for (int t = 0; t < 3; t++){
            g.s[t] = {xb[t], xb[t], Wint[t], b_in[t], nullptr, o[t], stats + t * 256,
                      Kin[t], Kin[t], Kin[t], Nn[t], Kin[t], tileBase[t], 1.0f};
        }
        gemmAll_k<128, true, true><<<tileBase[3], 256, 0, stream>>>(g);
        BnDesc bnd{}; int ib = 0;
        for (int t = 0; t < 3; t++){
            bnd.s[t] = {o[t], stats + t * 256, g_in + t * 128, bt_in + t * 128, h[t],
                        Nn[t], 1.0f / Nn[t], 0, ib};
            ib += Nn[t] * 16;
        }
        bnd.total = ib;
        bnAll_k<<<cdiv(ib, 256), 256, 0, stream>>>(bnd);
    }

    // ---- 3 conv layers ----
    const int e1s[3] = {1, 0, 2}, e2s[3] = {5, 3, 4};
    for (int L = 0; L < 3; L++){
        GDesc gd; int bacc = 0;
        gd.zrow = zrow;
        for (int t = 0; t < 6; t++){
            gd.s[t].offs = offs[t];
            gd.s[t].csr  = csr[t];
            gd.s[t].h    = (const uint4*)h[srcT[t]];
            gd.s[t].A    = (uint4*)A[dstT[t]];
            gd.s[t].colPair4 = colPair4_t[t];
            gd.s[t].N    = Ndst_t[t];
            gd.s[t].base = bacc;
            bacc += cdiv(Ndst_t[t], 16);
        }
        gatherall_k<<<bacc, 256, 0, stream>>>(gd);
        GemmDesc g{};
        for (int t = 0; t < 3; t++){
            int e1 = e1s[t], e2 = e2s[t];
            g.s[t] = {A[t], h[t], Wcat_t + (size_t)(L * 3 + t) * 128 * 384,
                      bl + (size_t)(L * 6 + e1) * 128, bl + (size_t)(L * 6 + e2) * 128,
                      o[t], stats + (size_t)(3 + L * 3 + t) * 256,
                      256, 128, 256, Nn[t], 384, tileBase[t], 0.5f};
        }
        gemmAll_k<128, true, true><<<tileBase[3], 256, 0, stream>>>(g);
        BnDesc bnd{}; int ib = 0;
        for (int t = 0; t < 3; t++){
            bnd.s[t] = {o[t], stats + (size_t)(3 + L * 3 + t) * 256,
                        g_conv + (size_t)(L * 3 + t) * 128, bt_conv + (size_t)(L * 3 + t) * 128,
                        h[t], Nn[t], 1.0f / Nn[t], 1, ib};
            ib += Nn[t] * 16;
        }
        bnd.total = ib;
        bnAll_k<<<cdiv(ib, 256), 256, 0, stream>>>(bnd);
    }

    // ---- final projection: one GEMM over contiguous h pool ----
    {
        int Ntot = ND + NG + NS;
        GemmDesc g{};
        g.s[0] = {h[0], h[0], Wfin_t, b_fin, nullptr, out, nullptr,
                  128, 128, 128, Ntot, 128, 0, 1.0f};
        g.s[1] = g.s[0]; g.s[1].tileBase = 0x3FFFFFFF; g.s[1].N = 0;
        g.s[2] = g.s[1];
        gemmAll_k<64, false, false><<<cdiv(Ntot, 128), 256, 0, stream>>>(g);
    }
}

// Round 11
// 540.321 us; speedup vs baseline: 1.0365x; 1.0365x over previous
//
#include <hip/hip_runtime.h>
#include <cstddef>
#include <cstdint>

typedef _Float16 f16;
typedef _Float16 f16x8 __attribute__((ext_vector_type(8)));
typedef float f32x4 __attribute__((ext_vector_type(4)));

constexpr int ND = 30000, NG = 60000, NS = 15000;
constexpr float BN_EPS = 1e-5f;
constexpr int NBUCK = 64;      // buckets per edge type
constexpr int TBUCK = 6 * NBUCK;
constexpr int PCHUNK = 4096;   // edges per partition block

static inline int cdiv(int a, int b){ return (a + b - 1) / b; }

// ================= bucketed CSR construction =================

struct BDesc {
    const int* src[6]; const int* dst[6];
    int Ebase[7]; int shift[6]; int N[6];
    int* bCnt; int* bBase; int* bCursor;
    uint2* packed;
    int* offs[6]; int* csr[6];
};

__global__ __launch_bounds__(256) void bhist_k(BDesc bd){
    __shared__ int hist[TBUCK];
    int tid = threadIdx.x;
    for (int i = tid; i < TBUCK; i += 256) hist[i] = 0;
    __syncthreads();
    int Etot = bd.Ebase[6];
    #pragma unroll
    for (int u = 0; u < 16; u++){
        int e = blockIdx.x * PCHUNK + u * 256 + tid;
        if (e < Etot){
            int t = 0;
            #pragma unroll
            for (int i = 1; i < 6; i++) if (e >= bd.Ebase[i]) t = i;
            int d = bd.dst[t][e - bd.Ebase[t]];
            atomicAdd(&hist[t * NBUCK + (d >> bd.shift[t])], 1);
        }
    }
    __syncthreads();
    for (int i = tid; i < TBUCK; i += 256)
        if (hist[i]) atomicAdd(&bd.bCnt[i], hist[i]);
}

__global__ __launch_bounds__(512) void bscan_k(BDesc bd){
    __shared__ int sh[TBUCK];
    int tid = threadIdx.x;
    int my = (tid < TBUCK) ? bd.bCnt[tid] : 0;
    if (tid < TBUCK) sh[tid] = my;
    __syncthreads();
    for (int d = 1; d < TBUCK; d <<= 1){
        int v = (tid < TBUCK) ? sh[tid] : 0;
        int add = (tid >= d && tid < TBUCK) ? sh[tid - d] : 0;
        __syncthreads();
        if (tid < TBUCK) sh[tid] = v + add;
        __syncthreads();
    }
    if (tid < TBUCK){
        int excl = sh[tid] - my;
        bd.bBase[tid] = excl;
        bd.bCursor[tid] = excl;
    }
    if (tid == 0) bd.bBase[TBUCK] = sh[TBUCK - 1];
}

__global__ __launch_bounds__(256) void bpart_k(BDesc bd){
    __shared__ int hist[TBUCK];
    __shared__ int basesh[TBUCK];
    int tid = threadIdx.x;
    for (int i = tid; i < TBUCK; i += 256) hist[i] = 0;
    __syncthreads();
    int Etot = bd.Ebase[6];
    int mb[16], mr[16], ms[16], md[16];
    #pragma unroll
    for (int u = 0; u < 16; u++){
        int e = blockIdx.x * PCHUNK + u * 256 + tid;
        mb[u] = -1;
        if (e < Etot){
            int t = 0;
            #pragma unroll
            for (int i = 1; i < 6; i++) if (e >= bd.Ebase[i]) t = i;
            int le = e - bd.Ebase[t];
            int s = bd.src[t][le], d = bd.dst[t][le];
            int b = t * NBUCK + (d >> bd.shift[t]);
            mr[u] = atomicAdd(&hist[b], 1);
            mb[u] = b; ms[u] = s; md[u] = d;
        }
    }
    __syncthreads();
    for (int i = tid; i < TBUCK; i += 256)
        basesh[i] = hist[i] ? atomicAdd(&bd.bCursor[i], hist[i]) : 0;
    __syncthreads();
    #pragma unroll
    for (int u = 0; u < 16; u++){
        if (mb[u] >= 0){
            int pos = basesh[mb[u]] + mr[u];
            bd.packed[pos] = make_uint2((unsigned)ms[u], (unsigned)md[u]);
        }
    }
}

// one block per bucket: count -> scan -> offs -> fill (all LDS-local)
__global__ __launch_bounds__(256) void bucketCsr_k(BDesc bd){
    __shared__ int cnt[1024];
    __shared__ int sh[256];
    int b = blockIdx.x;
    int t = b >> 6;          // /NBUCK
    int bb = b & 63;
    int tid = threadIdx.x;
    int shift = bd.shift[t];
    int nodeBase = bb << shift;
    int Nt = bd.N[t];
    int span = 1 << shift;   // <= 1024
    int tbase = bd.bBase[t * NBUCK];
    int eBeg = bd.bBase[b], eEnd = bd.bBase[b + 1];
    int bLocal = eBeg - tbase;
    #pragma unroll
    for (int i = 0; i < 4; i++) cnt[tid + i * 256] = 0;
    __syncthreads();
    for (int e = eBeg + tid; e < eEnd; e += 256)
        atomicAdd(&cnt[(int)bd.packed[e].y - nodeBase], 1);
    __syncthreads();
    int c0 = cnt[tid * 4], c1 = cnt[tid * 4 + 1], c2 = cnt[tid * 4 + 2], c3 = cnt[tid * 4 + 3];
    int s = c0 + c1 + c2 + c3;
    sh[tid] = s;
    __syncthreads();
    for (int d = 1; d < 256; d <<= 1){
        int v = sh[tid];
        int add = (tid >= d) ? sh[tid - d] : 0;
        __syncthreads();
        sh[tid] = v + add;
        __syncthreads();
    }
    int run = sh[tid] - s;
    int idx = tid * 4;
    int ex0 = run, ex1 = run + c0, ex2 = ex1 + c1, ex3 = ex2 + c2;
    if (idx     < span && nodeBase + idx     < Nt) bd.offs[t][nodeBase + idx]     = bLocal + ex0;
    if (idx + 1 < span && nodeBase + idx + 1 < Nt) bd.offs[t][nodeBase + idx + 1] = bLocal + ex1;
    if (idx + 2 < span && nodeBase + idx + 2 < Nt) bd.offs[t][nodeBase + idx + 2] = bLocal + ex2;
    if (idx + 3 < span && nodeBase + idx + 3 < Nt) bd.offs[t][nodeBase + idx + 3] = bLocal + ex3;
    cnt[idx] = ex0; cnt[idx + 1] = ex1; cnt[idx + 2] = ex2; cnt[idx + 3] = ex3;
    __syncthreads();
    for (int e = eBeg + tid; e < eEnd; e += 256){
        uint2 p = bd.packed[e];
        int lpos = atomicAdd(&cnt[(int)p.y - nodeBase], 1);
        bd.csr[t][bLocal + lpos] = (int)p.x;
    }
    if (bb == NBUCK - 1 && tid == 0)
        bd.offs[t][Nt] = bd.bBase[(t + 1) * NBUCK] - tbase;
}

// ================= weight transposes =================

struct WDesc {
    const float* W_in0; const float* W_in1; const float* W_in2;
    const float* W_fin; const float* Wl; const float* Wr;
    f16* Wint0; f16* Wint1; f16* Wint2; f16* Wfin_t; f16* Wcat_t;
};

__global__ __launch_bounds__(256) void weightAll_k(WDesc wd){
    int idx = blockIdx.x * 256 + threadIdx.x;
    if (idx < 32768){
        int c = idx >> 8, k = idx & 255;
        wd.Wint0[idx] = (f16)wd.W_in0[k * 128 + c];
    } else if (idx < 49152){
        int l = idx - 32768; int c = l >> 7, k = l & 127;
        wd.Wint1[l] = (f16)wd.W_in1[k * 128 + c];
    } else if (idx < 57344){
        int l = idx - 49152; int c = l >> 6, k = l & 63;
        wd.Wint2[l] = (f16)wd.W_in2[k * 128 + c];
    } else if (idx < 65536){
        int l = idx - 57344; int c = l >> 7, k = l & 127;
        wd.Wfin_t[l] = (f16)wd.W_fin[k * 64 + c];
    } else if (idx < 507904){
        int l = idx - 65536;
        int g = l / (384 * 128);
        int rem = l - g * (384 * 128);
        int c = rem / 384;
        int k = rem - c * 384;
        int L = g / 3, t = g - L * 3;
        const int e1s[3] = {1, 0, 2}, e2s[3] = {5, 3, 4};
        int e1 = e1s[t], e2 = e2s[t];
        float v;
        if (k < 128)      v = wd.Wl[(((size_t)L * 6 + e1) * 128 + k) * 128 + c];
        else if (k < 256) v = wd.Wl[(((size_t)L * 6 + e2) * 128 + (k - 128)) * 128 + c];
        else {
            int kr = k - 256;
            v = wd.Wr[(((size_t)L * 6 + e1) * 128 + kr) * 128 + c]
              + wd.Wr[(((size_t)L * 6 + e2) * 128 + kr) * 128 + c];
        }
        wd.Wcat_t[l] = (f16)v;
    }
}

// ================= fused gather-mean: 16-lane group per node, 8 rows in flight =================

struct GSeg { const int* offs; const int* csr; const uint4* h; uint4* A; int colPair4; int N; int base; };
struct GDesc { GSeg s[6]; const uint4* zrow; };

__device__ __forceinline__ f16x8 as_h8(uint4 v){
    union { uint4 u; f16x8 h; } c; c.u = v; return c.h;
}

__global__ __launch_bounds__(256) void gatherall_k(GDesc gd){
    int bid = blockIdx.x;
    int si = 0;
    #pragma unroll
    for (int t = 1; t < 6; t++) if (bid >= gd.s[t].base) si = t;
    GSeg sg = gd.s[si];
    int node = (bid - sg.base) * 16 + (threadIdx.x >> 4);
    if (node >= sg.N) return;
    int li = threadIdx.x & 15;
    int s = sg.offs[node], e = sg.offs[node + 1];
    const int* cp = sg.csr;
    const uint4* hp = sg.h;
    const uint4* zr = gd.zrow;
    f16x8 a = {};
    for (int j = s; j < e; j += 8){
        const uint4* p0 = (j + 0 < e) ? (hp + (size_t)cp[j + 0] * 16) : zr;
        const uint4* p1 = (j + 1 < e) ? (hp + (size_t)cp[j + 1] * 16) : zr;
        const uint4* p2 = (j + 2 < e) ? (hp + (size_t)cp[j + 2] * 16) : zr;
        const uint4* p3 = (j + 3 < e) ? (hp + (size_t)cp[j + 3] * 16) : zr;
        const uint4* p4 = (j + 4 < e) ? (hp + (size_t)cp[j + 4] * 16) : zr;
        const uint4* p5 = (j + 5 < e) ? (hp + (size_t)cp[j + 5] * 16) : zr;
        const uint4* p6 = (j + 6 < e) ? (hp + (size_t)cp[j + 6] * 16) : zr;
        const uint4* p7 = (j + 7 < e) ? (hp + (size_t)cp[j + 7] * 16) : zr;
        uint4 v0 = p0[li], v1 = p1[li], v2 = p2[li], v3 = p3[li];
        uint4 v4 = p4[li], v5 = p5[li], v6 = p6[li], v7 = p7[li];
        a = a + as_h8(v0); a = a + as_h8(v1); a = a + as_h8(v2); a = a + as_h8(v3);
        a = a + as_h8(v4); a = a + as_h8(v5); a = a + as_h8(v6); a = a + as_h8(v7);
    }
    float inv = (e > s) ? 1.0f / (float)(e - s) : 0.f;
    union { uint4 u; f16 h[8]; } pk;
    #pragma unroll
    for (int i = 0; i < 8; i++) pk.h[i] = (f16)((float)a[i] * inv);
    sg.A[(size_t)node * 32 + sg.colPair4 + li] = pk.u;
}

// ================= merged MFMA fp16 GEMM: global_load_lds + XOR swizzle =================
// A32=true: A source is fp32; staged via reg-load + cvt + swizzled ds_write (row-guarded).

struct GemmSeg {
    const f16* A1; const f16* A2; const f16* Wt;
    const float* b1; const float* b2; void* out; float* stats;
    int lda1, lda2, ksplit, N, K, tileBase; float scale;
};
struct GemmDesc { GemmSeg s[3]; };

template<int BN, bool STATS, bool OUT16, bool A32>
__global__ __launch_bounds__(256) void gemmAll_k(GemmDesc gd){
    constexpr int CF = BN / 16;
    __shared__ f16 As[128 * 64];
    __shared__ f16 Bs[BN * 64];
    __shared__ float ssum[BN];
    __shared__ float ssq[BN];
    int bid = blockIdx.x;
    int si = 0;
    #pragma unroll
    for (int t = 1; t < 3; t++) if (bid >= gd.s[t].tileBase) si = t;
    GemmSeg sg = gd.s[si];
    int tid = threadIdx.x;
    int wv = tid >> 6, lane = tid & 63;
    int row0 = (bid - sg.tileBase) * 128;
    int N = sg.N, K = sg.K;
    if (STATS && tid < BN){ ssum[tid] = 0.f; ssq[tid] = 0.f; }

    int rsub = lane >> 3;          // 0..7
    int seg  = lane & 7;
    int sseg = seg ^ rsub;         // inverse-swizzled global segment

    f32x4 acc[2][CF];
    #pragma unroll
    for (int rf = 0; rf < 2; rf++)
        #pragma unroll
        for (int cf = 0; cf < CF; cf++)
            acc[rf][cf] = (f32x4){0.f, 0.f, 0.f, 0.f};

    for (int k0 = 0; k0 < K; k0 += 64){
        if (A32){
            // fp32 A source: reg-load 8 floats, cvt, swizzled ds_write (16B)
            const float* Af = (const float*)sg.A1;
            int lda = sg.lda1;
            #pragma unroll
            for (int p = 0; p < 4; p++){
                int sidx = tid + p * 256;         // 0..1023
                int r = sidx >> 3, sg8 = sidx & 7;
                int gr = row0 + r;
                int gseg = sg8 ^ (r & 7);
                float4 u0 = make_float4(0.f, 0.f, 0.f, 0.f), u1 = u0;
                if (gr < N){
                    const float* ap = Af + (size_t)gr * lda + k0 + gseg * 8;
                    u0 = *reinterpret_cast<const float4*>(ap);
                    u1 = *reinterpret_cast<const float4*>(ap + 4);
                }
                union { uint4 u; f16 h[8]; } pk;
                pk.h[0] = (f16)u0.x; pk.h[1] = (f16)u0.y; pk.h[2] = (f16)u0.z; pk.h[3] = (f16)u0.w;
                pk.h[4] = (f16)u1.x; pk.h[5] = (f16)u1.y; pk.h[6] = (f16)u1.z; pk.h[7] = (f16)u1.w;
                *reinterpret_cast<uint4*>(&As[r * 64 + sg8 * 8]) = pk.u;
            }
        } else {
            const f16* Ab; int lda, kloc;
            if (k0 < sg.ksplit){ Ab = sg.A1; lda = sg.lda1; kloc = k0; }
            else               { Ab = sg.A2; lda = sg.lda2; kloc = k0 - sg.ksplit; }
            #pragma unroll
            for (int p = 0; p < 4; p++){
                int r = wv * 32 + p * 8 + rsub;
                const f16* srca = Ab + (size_t)(row0 + r) * lda + kloc + sseg * 8;
                __builtin_amdgcn_global_load_lds(
                    (const __attribute__((address_space(1))) void*)srca,
                    (__attribute__((address_space(3))) void*)&As[(wv * 32 + p * 8) * 64],
                    16, 0, 0);
            }
        }
        #pragma unroll
        for (int p = 0; p < BN / 32; p++){
            int c0 = wv * (BN / 4) + p * 8;
            const f16* srcb = sg.Wt + (size_t)(c0 + rsub) * K + k0 + sseg * 8;
            __builtin_amdgcn_global_load_lds(
                (const __attribute__((address_space(1))) void*)srcb,
                (__attribute__((address_space(3))) void*)&Bs[c0 * 64],
                16, 0, 0);
        }
        __syncthreads();
        #pragma unroll
        for (int kf = 0; kf < 2; kf++){
            int kidx = kf * 4 + (lane >> 4);
            int ar0 = wv * 32 + (lane & 15);
            int ar1 = ar0 + 16;
            f16x8 a0 = *reinterpret_cast<const f16x8*>(&As[ar0 * 64 + ((kidx ^ (ar0 & 7)) * 8)]);
            f16x8 a1 = *reinterpret_cast<const f16x8*>(&As[ar1 * 64 + ((kidx ^ (ar1 & 7)) * 8)]);
            #pragma unroll
            for (int cf = 0; cf < CF; cf++){
                int bc = cf * 16 + (lane & 15);
                f16x8 b = *reinterpret_cast<const f16x8*>(&Bs[bc * 64 + ((kidx ^ (bc & 7)) * 8)]);
                acc[0][cf] = __builtin_amdgcn_mfma_f32_16x16x32_f16(a0, b, acc[0][cf], 0, 0, 0);
                acc[1][cf] = __builtin_amdgcn_mfma_f32_16x16x32_f16(a1, b, acc[1][cf], 0, 0, 0);
            }
        }
        __syncthreads();
    }
    int rbase = row0 + wv * 32 + ((lane >> 4) << 2);
    #pragma unroll
    for (int cf = 0; cf < CF; cf++){
        int col = cf * 16 + (lane & 15);
        float bias = 0.f;
        if (sg.b1) bias += sg.b1[col];
        if (sg.b2) bias += sg.b2[col];
        float ls = 0.f, lq = 0.f;
        #pragma unroll
        for (int rf = 0; rf < 2; rf++){
            #pragma unroll
            for (int q = 0; q < 4; q++){
                int gr = rbase + rf * 16 + q;
                if (gr < N){
                    float v = sg.scale * (acc[rf][cf][q] + bias);
                    if (OUT16) ((f16*)sg.out)[(size_t)gr * BN + col] = (f16)v;
                    else       ((float*)sg.out)[(size_t)gr * BN + col] = v;
                    ls += v; lq += v * v;
                }
            }
        }
        if (STATS){ atomicAdd(&ssum[col], ls); atomicAdd(&ssq[col], lq); }
    }
    if (STATS){
        __syncthreads();
        if (tid < BN){
            atomicAdd(&sg.stats[tid], ssum[tid]);
            atomicAdd(&sg.stats[128 + tid], ssq[tid]);
        }
    }
}

// ================= merged BN apply + ReLU (+ residual) =================

struct BnSeg { const f16* o; const float* stats; const float* g; const float* b; f16* h; int N; float invN; int residual; int idxBase; };
struct BnDesc { BnSeg s[3]; int total; };

__global__ __launch_bounds__(256) void bnAll_k(BnDesc bd){
    int idx = blockIdx.x * 256 + threadIdx.x;
    if (idx >= bd.total) return;
    int si = 0;
    #pragma unroll
    for (int t = 1; t < 3; t++) if (idx >= bd.s[t].idxBase) si = t;
    BnSeg sg = bd.s[si];
    int l = idx - sg.idxBase;
    int n = l >> 4, c8 = (l & 15) * 8;
    union { uint4 u; f16 h[8]; } ov;
    ov.u = *reinterpret_cast<const uint4*>(sg.o + (size_t)n * 128 + c8);
    float r[8];
    #pragma unroll
    for (int j = 0; j < 8; j++){
        int c = c8 + j;
        float mu  = sg.stats[c] * sg.invN;
        float var = sg.stats[128 + c] * sg.invN - mu * mu;
        float v = ((float)ov.h[j] - mu) * rsqrtf(var + BN_EPS) * sg.g[c] + sg.b[c];
        r[j] = v > 0.f ? v : 0.f;
    }
    f16* hp = sg.h + (size_t)n * 128 + c8;
    if (sg.residual){
        uint4 old = *reinterpret_cast<const uint4*>(hp);
        union { uint4 u; f16 h[8]; } ou; ou.u = old;
        #pragma unroll
        for (int j = 0; j < 8; j++) r[j] += (float)ou.h[j];
    }
    union { uint4 u; f16 h[8]; } pk;
    #pragma unroll
    for (int j = 0; j < 8; j++) pk.h[j] = (f16)r[j];
    *reinterpret_cast<uint4*>(hp) = pk.u;
}

// ================= host orchestration =================

extern "C" void kernel_launch(void* const* d_in, const int* in_sizes, int n_in,
                              void* d_out, int out_size, void* d_ws, size_t ws_size,
                              hipStream_t stream){
    const float* x_drug = (const float*)d_in[0];
    const float* x_gene = (const float*)d_in[1];
    const float* x_dis  = (const float*)d_in[2];
    const int* srcP[6] = {(const int*)d_in[3], (const int*)d_in[5], (const int*)d_in[7],
                          (const int*)d_in[9], (const int*)d_in[11], (const int*)d_in[13]};
    const int* dstP[6] = {(const int*)d_in[4], (const int*)d_in[6], (const int*)d_in[8],
                          (const int*)d_in[10], (const int*)d_in[12], (const int*)d_in[14]};
    const int  Et[6]   = {in_sizes[3], in_sizes[5], in_sizes[7], in_sizes[9], in_sizes[11], in_sizes[13]};
    const float* W_in[3] = {(const float*)d_in[15], (const float*)d_in[17], (const float*)d_in[19]};
    const float* b_in[3] = {(const float*)d_in[16], (const float*)d_in[18], (const float*)d_in[20]};
    const float* g_in  = (const float*)d_in[21];
    const float* bt_in = (const float*)d_in[22];
    const float* Wl    = (const float*)d_in[23];
    const float* Wr    = (const float*)d_in[24];
    const float* bl    = (const float*)d_in[25];
    const float* g_conv  = (const float*)d_in[26];
    const float* bt_conv = (const float*)d_in[27];
    const float* W_fin = (const float*)d_in[28];
    const float* b_fin = (const float*)d_in[29];
    float* out = (float*)d_out;

    // edge-type metadata (order: dg, gd, gs, sg, ds, sd)
    const int Ndst_t[6]     = {NG, ND, NS, NG, NS, ND};
    const int srcT[6]       = {0, 1, 1, 2, 0, 2};
    const int dstT[6]       = {1, 0, 2, 1, 2, 0};
    const int colPair4_t[6] = {0, 0, 0, 16, 16, 16};

    const int Nn[3]  = {ND, NG, NS};
    const int Kin[3] = {256, 128, 64};
    const float* xin[3] = {x_drug, x_gene, x_dis};

    // ---- workspace carve ----
    char* base = (char*)d_ws;
    size_t off = 0;
    auto alloc = [&](size_t bytes) -> char* {
        char* p = base + off; off += (bytes + 255) & ~(size_t)255; return p;
    };
    f16* h[3];  for (int t = 0; t < 3; t++) h[t]  = (f16*)alloc((size_t)Nn[t] * 128 * 2);
    f16* A[3];  for (int t = 0; t < 3; t++) A[t]  = (f16*)alloc((size_t)Nn[t] * 256 * 2);
    f16* Wint[3]; for (int t = 0; t < 3; t++) Wint[t] = (f16*)alloc((size_t)128 * Kin[t] * 2);
    f16* Wfin_t = (f16*)alloc((size_t)64 * 128 * 2);
    f16* Wcat_t = (f16*)alloc((size_t)9 * 128 * 384 * 2);
    // o pool (aliased by packed edge buffer during CSR build, which finishes first)
    char* oPool = alloc((size_t)(ND + NG + NS) * 128 * 2);
    f16* o[3];
    o[0] = (f16*)oPool; o[1] = o[0] + (size_t)ND * 128; o[2] = o[1] + (size_t)NG * 128;
    uint2* packed = (uint2*)oPool;
    float* stats = (float*)alloc(12 * 256 * 4);
    // zero pool: bucket counters + 256B zero row
    int* zeroPool = (int*)alloc((size_t)(TBUCK + 64) * 4);
    int* bCnt = zeroPool;
    const uint4* zrow = (const uint4*)(zeroPool + TBUCK);
    int* bBase   = (int*)alloc((TBUCK + 1) * 4);
    int* bCursor = (int*)alloc(TBUCK * 4);
    int *offs[6], *csr[6];
    for (int t = 0; t < 6; t++) offs[t] = (int*)alloc((size_t)(Ndst_t[t] + 1) * 4);
    for (int t = 0; t < 6; t++) csr[t]  = (int*)alloc((size_t)Et[t] * 4);

    hipMemsetAsync(zeroPool, 0, (size_t)(TBUCK + 64) * 4, stream);
    hipMemsetAsync(stats, 0, 12 * 256 * 4, stream);

    // ---- bucketed CSR build ----
    BDesc bd;
    {
        int ecum = 0;
        for (int t = 0; t < 6; t++){
            bd.src[t] = srcP[t]; bd.dst[t] = dstP[t];
            bd.Ebase[t] = ecum; ecum += Et[t];
            int sft = 0; while (((Ndst_t[t] - 1) >> sft) >= NBUCK) sft++;
            bd.shift[t] = sft;
            bd.N[t] = Ndst_t[t];
            bd.offs[t] = offs[t]; bd.csr[t] = csr[t];
        }
        bd.Ebase[6] = ecum;
        bd.bCnt = bCnt; bd.bBase = bBase; bd.bCursor = bCursor;
        bd.packed = packed;
    }
    int Etot = bd.Ebase[6];
    bhist_k<<<cdiv(Etot, PCHUNK), 256, 0, stream>>>(bd);
    bscan_k<<<1, 512, 0, stream>>>(bd);
    bpart_k<<<cdiv(Etot, PCHUNK), 256, 0, stream>>>(bd);
    bucketCsr_k<<<TBUCK, 256, 0, stream>>>(bd);

    // ---- weights ----
    WDesc wd = {W_in[0], W_in[1], W_in[2], W_fin, Wl, Wr,
                Wint[0], Wint[1], Wint[2], Wfin_t, Wcat_t};
    weightAll_k<<<cdiv(507904, 256), 256, 0, stream>>>(wd);

    int tiles[3]; for (int t = 0; t < 3; t++) tiles[t] = cdiv(Nn[t], 128);
    int tileBase[4] = {0, tiles[0], tiles[0] + tiles[1], tiles[0] + tiles[1] + tiles[2]};

    // ---- input stage: GEMM reads fp32 x directly (A32 path) ----
    {
        GemmDesc g{};
        for (int t = 0; t < 3; t++){
            g.s[t] = {(const f16*)xin[t], (const f16*)xin[t], Wint[t], b_in[t], nullptr,
                      o[t], stats + t * 256,
                      Kin[t], Kin[t], Kin[t], Nn[t], Kin[t], tileBase[t], 1.0f};
        }
        gemmAll_k<128, true, true, true><<<tileBase[3], 256, 0, stream>>>(g);
        BnDesc bnd{}; int ib = 0;
        for (int t = 0; t < 3; t++){
            bnd.s[t] = {o[t], stats + t * 256, g_in + t * 128, bt_in + t * 128, h[t],
                        Nn[t], 1.0f / Nn[t], 0, ib};
            ib += Nn[t] * 16;
        }
        bnd.total = ib;
        bnAll_k<<<cdiv(ib, 256), 256, 0, stream>>>(bnd);
    }

    // ---- 3 conv layers ----
    const int e1s[3] = {1, 0, 2}, e2s[3] = {5, 3, 4};
    for (int L = 0; L < 3; L++){
        GDesc gd; int bacc = 0;
        gd.zrow = zrow;
        for (int t = 0; t < 6; t++){
            gd.s[t].offs = offs[t];
            gd.s[t].csr  = csr[t];
            gd.s[t].h    = (const uint4*)h[srcT[t]];
            gd.s[t].A    = (uint4*)A[dstT[t]];
            gd.s[t].colPair4 = colPair4_t[t];
            gd.s[t].N    = Ndst_t[t];
            gd.s[t].base = bacc;
            bacc += cdiv(Ndst_t[t], 16);
        }
        gatherall_k<<<bacc, 256, 0, stream>>>(gd);
        GemmDesc g{};
        for (int t = 0; t < 3; t++){
            int e1 = e1s[t], e2 = e2s[t];
            g.s[t] = {A[t], h[t], Wcat_t + (size_t)(L * 3 + t) * 128 * 384,
                      bl + (size_t)(L * 6 + e1) * 128, bl + (size_t)(L * 6 + e2) * 128,
                      o[t], stats + (size_t)(3 + L * 3 + t) * 256,
                      256, 128, 256, Nn[t], 384, tileBase[t], 0.5f};
        }
        gemmAll_k<128, true, true, false><<<tileBase[3], 256, 0, stream>>>(g);
        BnDesc bnd{}; int ib = 0;
        for (int t = 0; t < 3; t++){
            bnd.s[t] = {o[t], stats + (size_t)(3 + L * 3 + t) * 256,
                        g_conv + (size_t)(L * 3 + t) * 128, bt_conv + (size_t)(L * 3 + t) * 128,
                        h[t], Nn[t], 1.0f / Nn[t], 1, ib};
            ib += Nn[t] * 16;
        }
        bnd.total = ib;
        bnAll_k<<<cdiv(ib, 256), 256, 0, stream>>>(bnd);
    }

    // ---- final projection: one GEMM over contiguous h pool ----
    {
        int Ntot = ND + NG + NS;
        GemmDesc g{};
        g.s[0] = {h[0], h[0], Wfin_t, b_fin, nullptr, out, nullptr,
                  128, 128, 128, Ntot, 128, 0, 1.0f};
        g.s[1] = g.s[0]; g.s[1].tileBase = 0x3FFFFFFF; g.s[1].N = 0;
        g.s[2] = g.s[1];
        gemmAll_k<64, false, false, false><<<cdiv(Ntot, 128), 256, 0, stream>>>(g);
    }
}